// Round 15
// baseline (171.626 us; speedup 1.0000x reference)
//
#include <hip/hip_runtime.h>
#include <hip/hip_bf16.h>
#include <string.h>

using short8 = __attribute__((ext_vector_type(8))) short;
using f32x4  = __attribute__((ext_vector_type(4))) float;
using f32x2  = __attribute__((ext_vector_type(2))) float;

#define POOLN     9216       // 144*64 elements (bf16) per image
#define FC1N      128
#define WT2_ELEMS 18432      // 36*64*8
#define WT2_BYTES 36864
#define H1S_STRIDE 36        // shorts per position row (72 B)

#define GLL16(gp, lp) __builtin_amdgcn_global_load_lds( \
    (const __attribute__((address_space(1))) void*)(gp), \
    (__attribute__((address_space(3))) void*)(lp), 16, 0, 0)

static __device__ __forceinline__ unsigned short f2bf(float f) {
  unsigned int u = __builtin_bit_cast(unsigned int, f);
  unsigned int r = (u + 0x7FFFu + ((u >> 16) & 1u)) >> 16;
  return (unsigned short)r;
}

// packed RNE pair convert -> v_cvt_pk_bf16_f32
static __device__ __forceinline__ unsigned int pkbf(float lo, float hi) {
  __hip_bfloat162 h2 = __float22bfloat162_rn(make_float2(lo, hi));
  unsigned int r;
  memcpy(&r, &h2, sizeof(r));
  return r;
}

// ---- one-off: w2 fp32 [64][32][9] -> wt2 bf16 fragment order [(tap*4+n)][lane][8]
__global__ __launch_bounds__(256) void k_wt2(const float* __restrict__ w2,
    unsigned short* __restrict__ wt2) {
  int idx = blockIdx.x * 256 + threadIdx.x;
  if (idx >= WT2_ELEMS) return;
  int j = idx & 7;
  int l = (idx >> 3) & 63;
  int tn = idx >> 9;            // 0..35
  int tap = tn >> 2, n = tn & 3;
  int oc = n * 16 + (l & 15);
  int ic = (l >> 4) * 8 + j;
  wt2[idx] = f2bf(w2[oc * 288 + ic * 9 + tap]);
}

// ---- one-off: fc1_w [128][9216 (oc*144+sp)] -> fw1t bf16 [128][9216 (sp*64+oc)] ----
__global__ __launch_bounds__(256) void k_fw1t(const float* __restrict__ w,
    unsigned short* __restrict__ wt) {
  int c = blockIdx.x;
  __shared__ float row[9216];
  int t = threadIdx.x;
  const float* src = w + (size_t)c * 9216;
  for (int i = t; i < 9216; i += 256) row[i] = src[i];
  __syncthreads();
  unsigned short* dst = wt + (size_t)c * 9216;
  for (int k = t; k < 9216; k += 256) {
    int sp = k >> 6, oc = k & 63;
    dst[k] = f2bf(row[oc * 144 + sp]);
  }
}

// ---- fused conv1+relu+conv2+relu+maxpool, row-thirds, 8 waves ----
// grid (nr, 3), 512 threads, 2 blocks/CU (55.6 KB LDS).
// NEW: wt2 staged to LDS via async global_load_lds at block top (overlaps
// conv1); conv2 B-frags become conflict-free ds_read_b128 (ln*16) with
// compiler lgkmcnt pipelining -> removes exposed L2 load latency.
// conv1: wave w -> 4 channels, reads x direct from global (L1).
// conv2: wave = (mr = w>>1 pooled row, nh = w&1 n-half); acc[3][2].
__global__ __launch_bounds__(512, 4) void kc_fused(const float* __restrict__ x,
    const float* __restrict__ w1, const float* __restrict__ b1,
    const unsigned short* __restrict__ wt2, const float* __restrict__ b2,
    unsigned short* __restrict__ pooled) {
  int img = blockIdx.x;
  int tt = blockIdx.y;
  __shared__ __align__(16) unsigned short h1s[260 * H1S_STRIDE];  // 18720 B
  __shared__ __align__(16) unsigned short wlds[WT2_ELEMS];        // 36864 B
  int t = threadIdx.x;
  int wv = t >> 6, ln = t & 63;
  int r0x = tt * 8;                      // first x/h1 global row of this third

  // async stage wt2 -> LDS (36 chunks of 1024 B), drained by the barrier
  {
    const char* gw = (const char*)wt2 + ln * 16;
    char* wb = (char*)wlds;
    #pragma unroll
    for (int i = 0; i < 5; ++i) {
      int cc = wv + i * 8;
      if (cc < 36) GLL16(gw + cc * 1024, wb + cc * 1024);
    }
  }

  // conv1 weights: 4 channels per wave as 2 f32x2 pairs (wave-uniform -> SGPR)
  int wvu = __builtin_amdgcn_readfirstlane(wv);
  f32x2 wp[2][9], bp[2];
  #pragma unroll
  for (int p = 0; p < 2; ++p) {
    int o = wvu * 4 + p * 2;
    bp[p] = (f32x2){b1[o], b1[o + 1]};
    #pragma unroll
    for (int q = 0; q < 9; ++q)
      wp[p][q] = (f32x2){w1[o * 9 + q], w1[(o + 1) * 9 + q]};
  }

  // conv1: lane -> column, 2 halves x 5 rows (local h1 rows 0..9), x from global
  if (ln < 52) {
    int half = (ln >= 26);
    int xcol = ln - half * 26;          // 0..25
    int y0 = half * 5;                  // local row base
    const float* xg = x + (size_t)img * 784 + (size_t)(r0x + y0) * 28 + xcol;
    float win[3][3];
    #pragma unroll
    for (int c = 0; c < 3; ++c) {
      win[1][c] = xg[c];
      win[2][c] = xg[28 + c];
    }
    #pragma unroll
    for (int i = 0; i < 5; ++i) {
      #pragma unroll
      for (int c = 0; c < 3; ++c) {
        win[0][c] = win[1][c];
        win[1][c] = win[2][c];
        win[2][c] = xg[(i + 2) * 28 + c];
      }
      f32x2 s[2] = {bp[0], bp[1]};
      #pragma unroll
      for (int r = 0; r < 3; ++r)
        #pragma unroll
        for (int c = 0; c < 3; ++c) {
          f32x2 wv2 = (f32x2){win[r][c], win[r][c]};
          #pragma unroll
          for (int p = 0; p < 2; ++p)
            s[p] = __builtin_elementwise_fma(wv2, wp[p][r * 3 + c], s[p]);
        }
      unsigned int packed[2];
      const f32x2 z2 = (f32x2){0.f, 0.f};
      #pragma unroll
      for (int p = 0; p < 2; ++p) {
        f32x2 sp = __builtin_elementwise_max(s[p], z2);
        packed[p] = pkbf(sp.x, sp.y);
      }
      int pos = (y0 + i) * 26 + xcol;
      unsigned short* dst = &h1s[pos * H1S_STRIDE + wvu * 4];
      *(uint2*)dst = make_uint2(packed[0], packed[1]);
    }
  }
  __syncthreads();   // h1s ready AND wt2 staging drained

  // ---- conv2 + pool: wave = (pooled row mr, n-half nh); 3 m-tiles x 2 n ----
  int col = ln & 15;
  int g = (ln >> 4) & 3;
  int mr = wv >> 1;          // 0..3: pooled row within third
  int nh = wv & 1;           // n-half: frags nh*2, nh*2+1

  int abase[3];
  #pragma unroll
  for (int i = 0; i < 3; ++i) {
    int y = 2 * mr + (col & 1);                    // local h1 row
    int xx = 8 * i + (col >> 1);
    abase[i] = (y * 26 + xx) * (H1S_STRIDE * 2) + g * 16;
  }

  f32x4 acc[3][2];
  #pragma unroll
  for (int m = 0; m < 3; ++m)
    #pragma unroll
    for (int n = 0; n < 2; ++n)
      acc[m][n] = (f32x4){0.f, 0.f, 0.f, 0.f};

  const char* hsb = (const char*)h1s;
  const char* wb = (const char*)wlds;
  #pragma unroll
  for (int tap = 0; tap < 9; ++tap) {
    int ky = tap / 3, kx = tap - ky * 3;
    int toff = (ky * 26 + kx) * (H1S_STRIDE * 2);
    short8 bf[2];
    #pragma unroll
    for (int n = 0; n < 2; ++n)
      bf[n] = *(const short8*)(wb + (tap * 4 + nh * 2 + n) * 1024 + ln * 16);
    #pragma unroll
    for (int m = 0; m < 3; ++m) {
      union { short8 v; uint2 d[2]; } af;
      af.d[0] = *(const uint2*)(hsb + abase[m] + toff);
      af.d[1] = *(const uint2*)(hsb + abase[m] + toff + 8);
      #pragma unroll
      for (int n = 0; n < 2; ++n)
        acc[m][n] = __builtin_amdgcn_mfma_f32_16x16x32_bf16(af.v, bf[n], acc[m][n], 0, 0, 0);
    }
  }

  float bias[2];
  #pragma unroll
  for (int n = 0; n < 2; ++n) bias[n] = b2[(nh * 2 + n) * 16 + col];
  unsigned short* pp = pooled + (size_t)img * POOLN;
  int pr = tt * 4 + mr;                            // global pooled row
  #pragma unroll
  for (int m = 0; m < 3; ++m) {
    int sp = pr * 12 + m * 4 + g;
    float rv[2];
    #pragma unroll
    for (int n = 0; n < 2; ++n) {
      f32x4 a = acc[m][n];
      float v = fmaxf(fmaxf(a[0], a[1]), fmaxf(a[2], a[3]));
      rv[n] = fmaxf(v + bias[n], 0.f);
    }
    unsigned int p01 = pkbf(rv[0], rv[1]);
    unsigned short* pr0 = pp + sp * 64 + nh * 32 + col;
    pr0[0]  = (unsigned short)p01;
    pr0[16] = (unsigned short)(p01 >> 16);
  }
}

// ---- fc1 via MFMA, split-K=4: pooled bf16 [nr][9216] @ fw1t bf16 [128][9216]^T
__global__ __launch_bounds__(256) void k3_fc1_mfma(
    const unsigned short* __restrict__ a, const unsigned short* __restrict__ w,
    float* __restrict__ part, int nrpad) {
  __shared__ __align__(16) unsigned short As[2][4096];   // [64][64] bf16 x2
  __shared__ __align__(16) unsigned short Bs[2][8192];   // [128][64] bf16 x2
  int row0 = blockIdx.x * 64;
  int kbase = blockIdx.y * 2304;
  int t = threadIdx.x;
  int wv = t >> 6, l = t & 63;
  int rsub = l >> 3;
  int src_sw = ((l & 7) ^ rsub) << 4;

  const char* abase = (const char*)a + (size_t)row0 * 18432;
  const char* bbase = (const char*)w;

  auto stage = [&](int buf, int step) {
    size_t k0b = (size_t)(kbase + step * 64) * 2;
    #pragma unroll
    for (int i = 0; i < 2; ++i) {
      int c = wv * 2 + i;
      GLL16(abase + (size_t)(c * 8 + rsub) * 18432 + k0b + src_sw,
            (char*)As[buf] + c * 1024);
    }
    #pragma unroll
    for (int i = 0; i < 4; ++i) {
      int c = wv * 4 + i;
      GLL16(bbase + (size_t)(c * 8 + rsub) * 18432 + k0b + src_sw,
            (char*)Bs[buf] + c * 1024);
    }
  };

  int wm = wv >> 1, wn = wv & 1;
  int lr = l & 15, g2 = l >> 4;
  int rdxor = (lr & 7) << 4;

  f32x4 acc[2][4];
  #pragma unroll
  for (int mf = 0; mf < 2; ++mf)
    #pragma unroll
    for (int nf = 0; nf < 4; ++nf)
      acc[mf][nf] = (f32x4){0.f, 0.f, 0.f, 0.f};

  stage(0, 0);
  __syncthreads();
  for (int s = 0; s < 36; ++s) {
    int cur = s & 1;
    if (s < 35) stage(cur ^ 1, s + 1);
    const char* Ab = (const char*)As[cur];
    const char* Bb = (const char*)Bs[cur];
    #pragma unroll
    for (int ksub = 0; ksub < 2; ++ksub) {
      int koff = (ksub * 64 + g2 * 16) ^ rdxor;
      short8 af0 = *(const short8*)(Ab + (wm * 32 + lr) * 128 + koff);
      short8 af1 = *(const short8*)(Ab + (wm * 32 + 16 + lr) * 128 + koff);
      short8 bf[4];
      #pragma unroll
      for (int nf = 0; nf < 4; ++nf)
        bf[nf] = *(const short8*)(Bb + (wn * 64 + nf * 16 + lr) * 128 + koff);
      #pragma unroll
      for (int nf = 0; nf < 4; ++nf) {
        acc[0][nf] = __builtin_amdgcn_mfma_f32_16x16x32_bf16(af0, bf[nf], acc[0][nf], 0, 0, 0);
        acc[1][nf] = __builtin_amdgcn_mfma_f32_16x16x32_bf16(af1, bf[nf], acc[1][nf], 0, 0, 0);
      }
    }
    __syncthreads();
  }

  float* pp = part + (size_t)blockIdx.y * nrpad * 128 + (size_t)row0 * 128;
  #pragma unroll
  for (int mf = 0; mf < 2; ++mf)
    #pragma unroll
    for (int nf = 0; nf < 4; ++nf)
      #pragma unroll
      for (int rr = 0; rr < 4; ++rr) {
        int r = wm * 32 + mf * 16 + g2 * 4 + rr;
        int c = wn * 64 + nf * 16 + lr;
        pp[r * 128 + c] = acc[mf][nf][rr];
      }
}

// ---- fused tail: reduce 4 split-K partials + bias + relu -> fc2 -> out ----
__global__ __launch_bounds__(256) void k_tail(const float* __restrict__ part,
    const float* __restrict__ fb1, const float* __restrict__ fw2,
    const float* __restrict__ fb2, float* __restrict__ out,
    int nr, int nrpad) {
  __shared__ float sh[2][128];
  int t = threadIdx.x;
  int r = t >> 7, c = t & 127;
  int row = blockIdx.x * 2 + r;
  size_t stride = (size_t)nrpad * 128;
  if (row < nr) {
    size_t i = (size_t)row * 128 + c;
    float s = part[i] + part[stride + i] + part[2 * stride + i] + part[3 * stride + i];
    sh[r][c] = fmaxf(s + fb1[c], 0.f);
  }
  __syncthreads();
  if (t < 20) {
    int rr = t / 10, j = t - rr * 10;
    int orow = blockIdx.x * 2 + rr;
    if (orow < nr) {
      const float4* hv = (const float4*)sh[rr];
      const float4* wv = (const float4*)(fw2 + (size_t)j * 128);
      float s = 0.f;
      #pragma unroll
      for (int q = 0; q < 32; ++q) {
        float4 h4 = hv[q];
        float4 w4 = wv[q];
        s = fmaf(h4.x, w4.x, s);
        s = fmaf(h4.y, w4.y, s);
        s = fmaf(h4.z, w4.z, s);
        s = fmaf(h4.w, w4.w, s);
      }
      out[(size_t)orow * 10 + j] = s + fb2[j];
    }
  }
}

extern "C" void kernel_launch(void* const* d_in, const int* in_sizes, int n_in,
                              void* d_out, int out_size, void* d_ws, size_t ws_size,
                              hipStream_t stream) {
  const float* x   = (const float*)d_in[0];
  const float* w1  = (const float*)d_in[1];
  const float* b1  = (const float*)d_in[2];
  const float* w2  = (const float*)d_in[3];
  const float* b2  = (const float*)d_in[4];
  const float* fw1 = (const float*)d_in[5];
  const float* fb1 = (const float*)d_in[6];
  const float* fw2 = (const float*)d_in[7];
  const float* fb2 = (const float*)d_in[8];
  float* out = (float*)d_out;

  const int B = in_sizes[0] / 784;

  unsigned short* wt2 = (unsigned short*)d_ws;                        // 36864 B
  unsigned short* fw1t = (unsigned short*)((char*)d_ws + WT2_BYTES);  // 2359296 B
  const size_t carve = WT2_BYTES + (size_t)9216 * 128 * 2;
  char* base = (char*)d_ws + carve;
  size_t avail = (ws_size > carve) ? ws_size - carve : 0;
  const size_t per_img = (size_t)POOLN * 2 + 2048;   // pooled + 4 partial rows
  int Bc = (int)(avail / per_img);
  if (Bc > B) Bc = B;
  Bc &= ~63;
  if (Bc < 64) Bc = 64;

  unsigned short* pooled = (unsigned short*)base;
  float* part = (float*)(base + (size_t)Bc * (POOLN * 2));

  k_wt2<<<(WT2_ELEMS + 255) / 256, 256, 0, stream>>>(w2, wt2);
  k_fw1t<<<128, 256, 0, stream>>>(fw1, fw1t);

  for (int i0 = 0; i0 < B; i0 += Bc) {
    int nr = (B - i0 < Bc) ? (B - i0) : Bc;
    int mtiles = (nr + 63) / 64;
    int nrpad = mtiles * 64;
    kc_fused<<<dim3(nr, 3), 512, 0, stream>>>(x + (size_t)i0 * 784, w1, b1,
                                              wt2, b2, pooled);
    k3_fc1_mfma<<<dim3(mtiles, 4), 256, 0, stream>>>(pooled, fw1t, part, nrpad);
    k_tail<<<(nr + 1) / 2, 256, 0, stream>>>(part, fb1, fw2, fb2,
                                             out + (size_t)i0 * 10, nr, nrpad);
  }
}

// Round 16
// 170.966 us; speedup vs baseline: 1.0039x; 1.0039x over previous
//
#include <hip/hip_runtime.h>
#include <hip/hip_bf16.h>
#include <string.h>

using short8 = __attribute__((ext_vector_type(8))) short;
using f32x4  = __attribute__((ext_vector_type(4))) float;
using f32x2  = __attribute__((ext_vector_type(2))) float;

#define POOLN     9216       // 144*64 elements (bf16) per image
#define FC1N      128
#define WT2_ELEMS 18432      // 36*64*8
#define WT2_BYTES 36864
#define H1S_STRIDE 36        // shorts per position row (72 B)
#define IPB       4          // images pipelined per block

#define GLL16(gp, lp) __builtin_amdgcn_global_load_lds( \
    (const __attribute__((address_space(1))) void*)(gp), \
    (__attribute__((address_space(3))) void*)(lp), 16, 0, 0)

static __device__ __forceinline__ unsigned short f2bf(float f) {
  unsigned int u = __builtin_bit_cast(unsigned int, f);
  unsigned int r = (u + 0x7FFFu + ((u >> 16) & 1u)) >> 16;
  return (unsigned short)r;
}

// packed RNE pair convert -> v_cvt_pk_bf16_f32
static __device__ __forceinline__ unsigned int pkbf(float lo, float hi) {
  __hip_bfloat162 h2 = __float22bfloat162_rn(make_float2(lo, hi));
  unsigned int r;
  memcpy(&r, &h2, sizeof(r));
  return r;
}

// ---- one-off: w2 fp32 [64][32][9] -> wt2 bf16 fragment order [(tap*4+n)][lane][8]
__global__ __launch_bounds__(256) void k_wt2(const float* __restrict__ w2,
    unsigned short* __restrict__ wt2) {
  int idx = blockIdx.x * 256 + threadIdx.x;
  if (idx >= WT2_ELEMS) return;
  int j = idx & 7;
  int l = (idx >> 3) & 63;
  int tn = idx >> 9;            // 0..35
  int tap = tn >> 2, n = tn & 3;
  int oc = n * 16 + (l & 15);
  int ic = (l >> 4) * 8 + j;
  wt2[idx] = f2bf(w2[oc * 288 + ic * 9 + tap]);
}

// ---- one-off: fc1_w [128][9216 (oc*144+sp)] -> fw1t bf16 [128][9216 (sp*64+oc)] ----
__global__ __launch_bounds__(256) void k_fw1t(const float* __restrict__ w,
    unsigned short* __restrict__ wt) {
  int c = blockIdx.x;
  __shared__ float row[9216];
  int t = threadIdx.x;
  const float* src = w + (size_t)c * 9216;
  for (int i = t; i < 9216; i += 256) row[i] = src[i];
  __syncthreads();
  unsigned short* dst = wt + (size_t)c * 9216;
  for (int k = t; k < 9216; k += 256) {
    int sp = k >> 6, oc = k & 63;
    dst[k] = f2bf(row[oc * 144 + sp]);
  }
}

// ---- pipelined conv1+relu+conv2+relu+maxpool, row-thirds, IPB=4 images ----
// grid (nr/IPB, 3), 512 threads. Double-buffered h1s[2] (37.4 KB).
// Iteration body: conv1(img p+1, buf^1) THEN conv2(img p, buf) in one stream;
// conv1's global-x loads + pk_fma fill conv2's ds_read->MFMA latency gaps.
// Register shape = R14-proven: conv1 4ch/wave, conv2 n-split acc[3][2].
__global__ __launch_bounds__(512, 4) void kc_pipe(const float* __restrict__ x,
    const float* __restrict__ w1, const float* __restrict__ b1,
    const unsigned short* __restrict__ wt2, const float* __restrict__ b2,
    unsigned short* __restrict__ pooled) {
  int g0 = blockIdx.x * IPB;
  int tt = blockIdx.y;
  __shared__ __align__(16) unsigned short h1s[2][260 * H1S_STRIDE];  // 37440 B
  int t = threadIdx.x;
  int wv = t >> 6, ln = t & 63;
  int r0x = tt * 8;                      // first x/h1 global row of this third

  // conv1 weights: 4 channels per wave as 2 f32x2 pairs (wave-uniform -> SGPR)
  int wvu = __builtin_amdgcn_readfirstlane(wv);
  f32x2 wp[2][9], bp[2];
  #pragma unroll
  for (int p = 0; p < 2; ++p) {
    int o = wvu * 4 + p * 2;
    bp[p] = (f32x2){b1[o], b1[o + 1]};
    #pragma unroll
    for (int q = 0; q < 9; ++q)
      wp[p][q] = (f32x2){w1[o * 9 + q], w1[(o + 1) * 9 + q]};
  }

  // conv1 lane geometry
  int half = (ln >= 26);
  int xcol = ln - half * 26;            // 0..25 (junk for ln>=52, store-masked)
  if (xcol > 25) xcol = 25;
  bool c1act = (ln < 52);
  int y0 = half * 5;

  // conv2 lane geometry: wave = (mr = wv>>1 pooled row, nh = wv&1 n-half)
  int col = ln & 15;
  int g = (ln >> 4) & 3;
  int mr = wv >> 1;
  int nh = wv & 1;
  int abase[3];
  #pragma unroll
  for (int i = 0; i < 3; ++i) {
    int y = 2 * mr + (col & 1);
    int xx = 8 * i + (col >> 1);
    abase[i] = (y * 26 + xx) * (H1S_STRIDE * 2) + g * 16;
  }
  float bias[2];
  #pragma unroll
  for (int n = 0; n < 2; ++n) bias[n] = b2[(nh * 2 + n) * 16 + col];

  auto conv1_body = [&](int img, int buf) {
    const float* xg = x + (size_t)img * 784 + (size_t)(r0x + y0) * 28 + xcol;
    float win[3][3];
    #pragma unroll
    for (int c = 0; c < 3; ++c) {
      win[1][c] = xg[c];
      win[2][c] = xg[28 + c];
    }
    #pragma unroll
    for (int i = 0; i < 5; ++i) {
      #pragma unroll
      for (int c = 0; c < 3; ++c) {
        win[0][c] = win[1][c];
        win[1][c] = win[2][c];
        win[2][c] = xg[(i + 2) * 28 + c];
      }
      f32x2 s[2] = {bp[0], bp[1]};
      #pragma unroll
      for (int r = 0; r < 3; ++r)
        #pragma unroll
        for (int c = 0; c < 3; ++c) {
          f32x2 wv2 = (f32x2){win[r][c], win[r][c]};
          #pragma unroll
          for (int p = 0; p < 2; ++p)
            s[p] = __builtin_elementwise_fma(wv2, wp[p][r * 3 + c], s[p]);
        }
      unsigned int packed[2];
      const f32x2 z2 = (f32x2){0.f, 0.f};
      #pragma unroll
      for (int p = 0; p < 2; ++p) {
        f32x2 sp = __builtin_elementwise_max(s[p], z2);
        packed[p] = pkbf(sp.x, sp.y);
      }
      if (c1act) {
        int pos = (y0 + i) * 26 + xcol;
        unsigned short* dst = &h1s[buf][pos * H1S_STRIDE + wvu * 4];
        *(uint2*)dst = make_uint2(packed[0], packed[1]);
      }
    }
  };

  auto conv2_body = [&](int img, int buf) {
    const char* hsb = (const char*)h1s[buf];
    f32x4 acc[3][2];
    #pragma unroll
    for (int m = 0; m < 3; ++m)
      #pragma unroll
      for (int n = 0; n < 2; ++n)
        acc[m][n] = (f32x4){0.f, 0.f, 0.f, 0.f};
    #pragma unroll
    for (int tap = 0; tap < 9; ++tap) {
      int ky = tap / 3, kx = tap - ky * 3;
      int toff = (ky * 26 + kx) * (H1S_STRIDE * 2);
      short8 bf[2];
      #pragma unroll
      for (int n = 0; n < 2; ++n)
        bf[n] = *(const short8*)(wt2 + ((size_t)(tap * 4 + nh * 2 + n) * 64 + ln) * 8);
      #pragma unroll
      for (int m = 0; m < 3; ++m) {
        union { short8 v; uint2 d[2]; } af;
        af.d[0] = *(const uint2*)(hsb + abase[m] + toff);
        af.d[1] = *(const uint2*)(hsb + abase[m] + toff + 8);
        #pragma unroll
        for (int n = 0; n < 2; ++n)
          acc[m][n] = __builtin_amdgcn_mfma_f32_16x16x32_bf16(af.v, bf[n], acc[m][n], 0, 0, 0);
      }
    }
    unsigned short* pp = pooled + (size_t)img * POOLN;
    int pr = tt * 4 + mr;
    #pragma unroll
    for (int m = 0; m < 3; ++m) {
      int sp = pr * 12 + m * 4 + g;
      float rv[2];
      #pragma unroll
      for (int n = 0; n < 2; ++n) {
        f32x4 a = acc[m][n];
        float v = fmaxf(fmaxf(a[0], a[1]), fmaxf(a[2], a[3]));
        rv[n] = fmaxf(v + bias[n], 0.f);
      }
      unsigned int p01 = pkbf(rv[0], rv[1]);
      unsigned short* pr0 = pp + sp * 64 + nh * 32 + col;
      pr0[0]  = (unsigned short)p01;
      pr0[16] = (unsigned short)(p01 >> 16);
    }
  };

  conv1_body(g0, 0);
  __syncthreads();
  #pragma unroll
  for (int p = 0; p < IPB; ++p) {
    if (p + 1 < IPB) conv1_body(g0 + p + 1, (p + 1) & 1);  // VALU + global loads
    conv2_body(g0 + p, p & 1);                             // LDS + MFMA
    __syncthreads();
  }
}

// ---- fc1 via MFMA, split-K=4: pooled bf16 [nr][9216] @ fw1t bf16 [128][9216]^T
__global__ __launch_bounds__(256) void k3_fc1_mfma(
    const unsigned short* __restrict__ a, const unsigned short* __restrict__ w,
    float* __restrict__ part, int nrpad) {
  __shared__ __align__(16) unsigned short As[2][4096];   // [64][64] bf16 x2
  __shared__ __align__(16) unsigned short Bs[2][8192];   // [128][64] bf16 x2
  int row0 = blockIdx.x * 64;
  int kbase = blockIdx.y * 2304;
  int t = threadIdx.x;
  int wv = t >> 6, l = t & 63;
  int rsub = l >> 3;
  int src_sw = ((l & 7) ^ rsub) << 4;

  const char* abase = (const char*)a + (size_t)row0 * 18432;
  const char* bbase = (const char*)w;

  auto stage = [&](int buf, int step) {
    size_t k0b = (size_t)(kbase + step * 64) * 2;
    #pragma unroll
    for (int i = 0; i < 2; ++i) {
      int c = wv * 2 + i;
      GLL16(abase + (size_t)(c * 8 + rsub) * 18432 + k0b + src_sw,
            (char*)As[buf] + c * 1024);
    }
    #pragma unroll
    for (int i = 0; i < 4; ++i) {
      int c = wv * 4 + i;
      GLL16(bbase + (size_t)(c * 8 + rsub) * 18432 + k0b + src_sw,
            (char*)Bs[buf] + c * 1024);
    }
  };

  int wm = wv >> 1, wn = wv & 1;
  int lr = l & 15, g2 = l >> 4;
  int rdxor = (lr & 7) << 4;

  f32x4 acc[2][4];
  #pragma unroll
  for (int mf = 0; mf < 2; ++mf)
    #pragma unroll
    for (int nf = 0; nf < 4; ++nf)
      acc[mf][nf] = (f32x4){0.f, 0.f, 0.f, 0.f};

  stage(0, 0);
  __syncthreads();
  for (int s = 0; s < 36; ++s) {
    int cur = s & 1;
    if (s < 35) stage(cur ^ 1, s + 1);
    const char* Ab = (const char*)As[cur];
    const char* Bb = (const char*)Bs[cur];
    #pragma unroll
    for (int ksub = 0; ksub < 2; ++ksub) {
      int koff = (ksub * 64 + g2 * 16) ^ rdxor;
      short8 af0 = *(const short8*)(Ab + (wm * 32 + lr) * 128 + koff);
      short8 af1 = *(const short8*)(Ab + (wm * 32 + 16 + lr) * 128 + koff);
      short8 bf[4];
      #pragma unroll
      for (int nf = 0; nf < 4; ++nf)
        bf[nf] = *(const short8*)(Bb + (wn * 64 + nf * 16 + lr) * 128 + koff);
      #pragma unroll
      for (int nf = 0; nf < 4; ++nf) {
        acc[0][nf] = __builtin_amdgcn_mfma_f32_16x16x32_bf16(af0, bf[nf], acc[0][nf], 0, 0, 0);
        acc[1][nf] = __builtin_amdgcn_mfma_f32_16x16x32_bf16(af1, bf[nf], acc[1][nf], 0, 0, 0);
      }
    }
    __syncthreads();
  }

  float* pp = part + (size_t)blockIdx.y * nrpad * 128 + (size_t)row0 * 128;
  #pragma unroll
  for (int mf = 0; mf < 2; ++mf)
    #pragma unroll
    for (int nf = 0; nf < 4; ++nf)
      #pragma unroll
      for (int rr = 0; rr < 4; ++rr) {
        int r = wm * 32 + mf * 16 + g2 * 4 + rr;
        int c = wn * 64 + nf * 16 + lr;
        pp[r * 128 + c] = acc[mf][nf][rr];
      }
}

// ---- fused tail: reduce 4 split-K partials + bias + relu -> fc2 -> out ----
__global__ __launch_bounds__(256) void k_tail(const float* __restrict__ part,
    const float* __restrict__ fb1, const float* __restrict__ fw2,
    const float* __restrict__ fb2, float* __restrict__ out,
    int nr, int nrpad) {
  __shared__ float sh[2][128];
  int t = threadIdx.x;
  int r = t >> 7, c = t & 127;
  int row = blockIdx.x * 2 + r;
  size_t stride = (size_t)nrpad * 128;
  if (row < nr) {
    size_t i = (size_t)row * 128 + c;
    float s = part[i] + part[stride + i] + part[2 * stride + i] + part[3 * stride + i];
    sh[r][c] = fmaxf(s + fb1[c], 0.f);
  }
  __syncthreads();
  if (t < 20) {
    int rr = t / 10, j = t - rr * 10;
    int orow = blockIdx.x * 2 + rr;
    if (orow < nr) {
      const float4* hv = (const float4*)sh[rr];
      const float4* wv = (const float4*)(fw2 + (size_t)j * 128);
      float s = 0.f;
      #pragma unroll
      for (int q = 0; q < 32; ++q) {
        float4 h4 = hv[q];
        float4 w4 = wv[q];
        s = fmaf(h4.x, w4.x, s);
        s = fmaf(h4.y, w4.y, s);
        s = fmaf(h4.z, w4.z, s);
        s = fmaf(h4.w, w4.w, s);
      }
      out[(size_t)orow * 10 + j] = s + fb2[j];
    }
  }
}

extern "C" void kernel_launch(void* const* d_in, const int* in_sizes, int n_in,
                              void* d_out, int out_size, void* d_ws, size_t ws_size,
                              hipStream_t stream) {
  const float* x   = (const float*)d_in[0];
  const float* w1  = (const float*)d_in[1];
  const float* b1  = (const float*)d_in[2];
  const float* w2  = (const float*)d_in[3];
  const float* b2  = (const float*)d_in[4];
  const float* fw1 = (const float*)d_in[5];
  const float* fb1 = (const float*)d_in[6];
  const float* fw2 = (const float*)d_in[7];
  const float* fb2 = (const float*)d_in[8];
  float* out = (float*)d_out;

  const int B = in_sizes[0] / 784;

  unsigned short* wt2 = (unsigned short*)d_ws;                        // 36864 B
  unsigned short* fw1t = (unsigned short*)((char*)d_ws + WT2_BYTES);  // 2359296 B
  const size_t carve = WT2_BYTES + (size_t)9216 * 128 * 2;
  char* base = (char*)d_ws + carve;
  size_t avail = (ws_size > carve) ? ws_size - carve : 0;
  const size_t per_img = (size_t)POOLN * 2 + 2048;   // pooled + 4 partial rows
  int Bc = (int)(avail / per_img);
  if (Bc > B) Bc = B;
  Bc &= ~63;
  if (Bc < 64) Bc = 64;

  unsigned short* pooled = (unsigned short*)base;
  float* part = (float*)(base + (size_t)Bc * (POOLN * 2));

  k_wt2<<<(WT2_ELEMS + 255) / 256, 256, 0, stream>>>(w2, wt2);
  k_fw1t<<<128, 256, 0, stream>>>(fw1, fw1t);

  for (int i0 = 0; i0 < B; i0 += Bc) {
    int nr = (B - i0 < Bc) ? (B - i0) : Bc;   // multiple of 64 -> /IPB exact
    int mtiles = (nr + 63) / 64;
    int nrpad = mtiles * 64;
    kc_pipe<<<dim3(nr / IPB, 3), 512, 0, stream>>>(x + (size_t)i0 * 784, w1, b1,
                                                   wt2, b2, pooled);
    k3_fc1_mfma<<<dim3(mtiles, 4), 256, 0, stream>>>(pooled, fw1t, part, nrpad);
    k_tail<<<(nr + 1) / 2, 256, 0, stream>>>(part, fb1, fw2, fb2,
                                             out + (size_t)i0 * 10, nr, nrpad);
  }
}

// Round 17
// 148.254 us; speedup vs baseline: 1.1576x; 1.1532x over previous
//
#include <hip/hip_runtime.h>
#include <hip/hip_bf16.h>
#include <string.h>

using short8 = __attribute__((ext_vector_type(8))) short;
using f32x4  = __attribute__((ext_vector_type(4))) float;
using f32x2  = __attribute__((ext_vector_type(2))) float;

#define POOLN     9216       // 144*64 elements (bf16) per image
#define FC1N      128
#define WT2_ELEMS 18432      // 36*64*8
#define WT2_BYTES 36864
#define H1S_STRIDE 36        // shorts per position row (72 B)
#define XS_STRIDE  29        // floats per x row (odd -> conflict-free)
#define SPLITK    8

#define GLL16(gp, lp) __builtin_amdgcn_global_load_lds( \
    (const __attribute__((address_space(1))) void*)(gp), \
    (__attribute__((address_space(3))) void*)(lp), 16, 0, 0)

static __device__ __forceinline__ unsigned short f2bf(float f) {
  unsigned int u = __builtin_bit_cast(unsigned int, f);
  unsigned int r = (u + 0x7FFFu + ((u >> 16) & 1u)) >> 16;
  return (unsigned short)r;
}

// packed RNE pair convert -> v_cvt_pk_bf16_f32
static __device__ __forceinline__ unsigned int pkbf(float lo, float hi) {
  __hip_bfloat162 h2 = __float22bfloat162_rn(make_float2(lo, hi));
  unsigned int r;
  memcpy(&r, &h2, sizeof(r));
  return r;
}

// ---- one-off: w2 fp32 [64][32][9] -> wt2 bf16 fragment order [(tap*4+n)][lane][8]
__global__ __launch_bounds__(256) void k_wt2(const float* __restrict__ w2,
    unsigned short* __restrict__ wt2) {
  int idx = blockIdx.x * 256 + threadIdx.x;
  if (idx >= WT2_ELEMS) return;
  int j = idx & 7;
  int l = (idx >> 3) & 63;
  int tn = idx >> 9;            // 0..35
  int tap = tn >> 2, n = tn & 3;
  int oc = n * 16 + (l & 15);
  int ic = (l >> 4) * 8 + j;
  wt2[idx] = f2bf(w2[oc * 288 + ic * 9 + tap]);
}

// ---- one-off: fc1_w [128][9216 (oc*144+sp)] -> fw1t bf16 [128][9216 (sp*64+oc)] ----
__global__ __launch_bounds__(256) void k_fw1t(const float* __restrict__ w,
    unsigned short* __restrict__ wt) {
  int c = blockIdx.x;
  __shared__ float row[9216];
  int t = threadIdx.x;
  const float* src = w + (size_t)c * 9216;
  for (int i = t; i < 9216; i += 256) row[i] = src[i];
  __syncthreads();
  unsigned short* dst = wt + (size_t)c * 9216;
  for (int k = t; k < 9216; k += 256) {
    int sp = k >> 6, oc = k & 63;
    dst[k] = f2bf(row[oc * 144 + sp]);
  }
}

// ---- fused conv1+relu+conv2+relu+maxpool, row-thirds (R12 best config) ----
// grid (nr, 3). conv1 packed fp32 (v_pk_fma_f32) channel pairs; conv2 wave =
// local pooled row, acc[3][4]=48 AGPR. LDS 20.1 KB, (256,4). + T5 setprio.
__global__ __launch_bounds__(256, 4) void kc_fused(const float* __restrict__ x,
    const float* __restrict__ w1, const float* __restrict__ b1,
    const unsigned short* __restrict__ wt2, const float* __restrict__ b2,
    unsigned short* __restrict__ pooled) {
  int img = blockIdx.x;
  int tt = blockIdx.y;
  __shared__ float xs[12 * XS_STRIDE];                            // 1392 B
  __shared__ __align__(16) unsigned short h1s[260 * H1S_STRIDE];  // 18720 B
  int t = threadIdx.x;
  int wv = t >> 6, ln = t & 63;
  int r0x = tt * 8;                      // first x/h1 global row of this third

  const float* xp = x + (size_t)img * 784 + (size_t)r0x * 28;
  for (int i = t; i < 12 * 28; i += 256) {
    int r = i / 28, c = i - r * 28;
    xs[r * XS_STRIDE + c] = xp[r * 28 + c];
  }

  // conv1 weights as channel-pair f32x2 (wave-uniform -> SGPR pairs)
  int wvu = __builtin_amdgcn_readfirstlane(wv);
  f32x2 wp[4][9], bp[4];
  #pragma unroll
  for (int p = 0; p < 4; ++p) {
    int o = wvu * 8 + p * 2;
    bp[p] = (f32x2){b1[o], b1[o + 1]};
    #pragma unroll
    for (int q = 0; q < 9; ++q)
      wp[p][q] = (f32x2){w1[o * 9 + q], w1[(o + 1) * 9 + q]};
  }
  __syncthreads();

  // conv1: lane -> column, 2 halves x 5 rows each (local h1 rows 0..9)
  if (ln < 52) {
    int half = (ln >= 26);
    int xcol = ln - half * 26;          // 0..25
    int y0 = half * 5;                  // local row base
    float win[3][3];
    #pragma unroll
    for (int c = 0; c < 3; ++c) {
      win[1][c] = xs[(y0 + 0) * XS_STRIDE + xcol + c];
      win[2][c] = xs[(y0 + 1) * XS_STRIDE + xcol + c];
    }
    #pragma unroll
    for (int i = 0; i < 5; ++i) {
      #pragma unroll
      for (int c = 0; c < 3; ++c) {
        win[0][c] = win[1][c];
        win[1][c] = win[2][c];
        win[2][c] = xs[(y0 + i + 2) * XS_STRIDE + xcol + c];
      }
      f32x2 s[4] = {bp[0], bp[1], bp[2], bp[3]};
      #pragma unroll
      for (int r = 0; r < 3; ++r)
        #pragma unroll
        for (int c = 0; c < 3; ++c) {
          f32x2 wv2 = (f32x2){win[r][c], win[r][c]};
          #pragma unroll
          for (int p = 0; p < 4; ++p)
            s[p] = __builtin_elementwise_fma(wv2, wp[p][r * 3 + c], s[p]);
        }
      unsigned int packed[4];
      const f32x2 z2 = (f32x2){0.f, 0.f};
      #pragma unroll
      for (int p = 0; p < 4; ++p) {
        f32x2 sp = __builtin_elementwise_max(s[p], z2);
        packed[p] = pkbf(sp.x, sp.y);
      }
      int pos = (y0 + i) * 26 + xcol;
      unsigned short* dst = &h1s[pos * H1S_STRIDE + wv * 8];
      *(uint2*)dst = make_uint2(packed[0], packed[1]);
      *(uint2*)(dst + 4) = make_uint2(packed[2], packed[3]);
    }
  }
  __syncthreads();

  // ---- conv2 + pool: wave = local pooled row, 3 m-tiles ----
  int col = ln & 15;
  int g = (ln >> 4) & 3;

  int abase[3];
  #pragma unroll
  for (int i = 0; i < 3; ++i) {
    int y = 2 * wv + (col & 1);                    // local h1 row
    int xx = 8 * i + (col >> 1);
    abase[i] = (y * 26 + xx) * (H1S_STRIDE * 2) + g * 16;
  }

  f32x4 acc[3][4];
  #pragma unroll
  for (int m = 0; m < 3; ++m)
    #pragma unroll
    for (int n = 0; n < 4; ++n)
      acc[m][n] = (f32x4){0.f, 0.f, 0.f, 0.f};

  const char* hsb = (const char*)h1s;
  __builtin_amdgcn_s_setprio(1);
  #pragma unroll
  for (int tap = 0; tap < 9; ++tap) {
    int ky = tap / 3, kx = tap - ky * 3;
    int toff = (ky * 26 + kx) * (H1S_STRIDE * 2);
    short8 bf[4];
    #pragma unroll
    for (int n = 0; n < 4; ++n)
      bf[n] = *(const short8*)(wt2 + ((size_t)(tap * 4 + n) * 64 + ln) * 8);
    #pragma unroll
    for (int m = 0; m < 3; ++m) {
      union { short8 v; uint2 d[2]; } af;
      af.d[0] = *(const uint2*)(hsb + abase[m] + toff);
      af.d[1] = *(const uint2*)(hsb + abase[m] + toff + 8);
      #pragma unroll
      for (int n = 0; n < 4; ++n)
        acc[m][n] = __builtin_amdgcn_mfma_f32_16x16x32_bf16(af.v, bf[n], acc[m][n], 0, 0, 0);
    }
  }
  __builtin_amdgcn_s_setprio(0);

  float bias[4];
  #pragma unroll
  for (int n = 0; n < 4; ++n) bias[n] = b2[n * 16 + col];
  unsigned short* pp = pooled + (size_t)img * POOLN;
  int pr = tt * 4 + wv;                            // global pooled row
  #pragma unroll
  for (int m = 0; m < 3; ++m) {
    int sp = pr * 12 + m * 4 + g;
    float rv[4];
    #pragma unroll
    for (int n = 0; n < 4; ++n) {
      f32x4 a = acc[m][n];
      float v = fmaxf(fmaxf(a[0], a[1]), fmaxf(a[2], a[3]));
      rv[n] = fmaxf(v + bias[n], 0.f);
    }
    unsigned int p01 = pkbf(rv[0], rv[1]);
    unsigned int p23 = pkbf(rv[2], rv[3]);
    unsigned short* pr0 = pp + sp * 64 + col;
    pr0[0]  = (unsigned short)p01;
    pr0[16] = (unsigned short)(p01 >> 16);
    pr0[32] = (unsigned short)p23;
    pr0[48] = (unsigned short)(p23 >> 16);
  }
}

// ---- fc1 via MFMA, split-K=8: pooled bf16 [nr][9216] @ fw1t bf16 [128][9216]^T
// grid (nrpad/64, 8); each group does 1152 K-elems = 18 steps of 64.
__global__ __launch_bounds__(256) void k3_fc1_mfma(
    const unsigned short* __restrict__ a, const unsigned short* __restrict__ w,
    float* __restrict__ part, int nrpad) {
  __shared__ __align__(16) unsigned short As[2][4096];   // [64][64] bf16 x2
  __shared__ __align__(16) unsigned short Bs[2][8192];   // [128][64] bf16 x2
  int row0 = blockIdx.x * 64;
  int kbase = blockIdx.y * 1152;
  int t = threadIdx.x;
  int wv = t >> 6, l = t & 63;
  int rsub = l >> 3;
  int src_sw = ((l & 7) ^ rsub) << 4;

  const char* abase = (const char*)a + (size_t)row0 * 18432;
  const char* bbase = (const char*)w;

  auto stage = [&](int buf, int step) {
    size_t k0b = (size_t)(kbase + step * 64) * 2;
    #pragma unroll
    for (int i = 0; i < 2; ++i) {
      int c = wv * 2 + i;
      GLL16(abase + (size_t)(c * 8 + rsub) * 18432 + k0b + src_sw,
            (char*)As[buf] + c * 1024);
    }
    #pragma unroll
    for (int i = 0; i < 4; ++i) {
      int c = wv * 4 + i;
      GLL16(bbase + (size_t)(c * 8 + rsub) * 18432 + k0b + src_sw,
            (char*)Bs[buf] + c * 1024);
    }
  };

  int wm = wv >> 1, wn = wv & 1;
  int lr = l & 15, g2 = l >> 4;
  int rdxor = (lr & 7) << 4;

  f32x4 acc[2][4];
  #pragma unroll
  for (int mf = 0; mf < 2; ++mf)
    #pragma unroll
    for (int nf = 0; nf < 4; ++nf)
      acc[mf][nf] = (f32x4){0.f, 0.f, 0.f, 0.f};

  stage(0, 0);
  __syncthreads();
  for (int s = 0; s < 18; ++s) {
    int cur = s & 1;
    if (s < 17) stage(cur ^ 1, s + 1);
    const char* Ab = (const char*)As[cur];
    const char* Bb = (const char*)Bs[cur];
    #pragma unroll
    for (int ksub = 0; ksub < 2; ++ksub) {
      int koff = (ksub * 64 + g2 * 16) ^ rdxor;
      short8 af0 = *(const short8*)(Ab + (wm * 32 + lr) * 128 + koff);
      short8 af1 = *(const short8*)(Ab + (wm * 32 + 16 + lr) * 128 + koff);
      short8 bf[4];
      #pragma unroll
      for (int nf = 0; nf < 4; ++nf)
        bf[nf] = *(const short8*)(Bb + (wn * 64 + nf * 16 + lr) * 128 + koff);
      #pragma unroll
      for (int nf = 0; nf < 4; ++nf) {
        acc[0][nf] = __builtin_amdgcn_mfma_f32_16x16x32_bf16(af0, bf[nf], acc[0][nf], 0, 0, 0);
        acc[1][nf] = __builtin_amdgcn_mfma_f32_16x16x32_bf16(af1, bf[nf], acc[1][nf], 0, 0, 0);
      }
    }
    __syncthreads();
  }

  float* pp = part + (size_t)blockIdx.y * nrpad * 128 + (size_t)row0 * 128;
  #pragma unroll
  for (int mf = 0; mf < 2; ++mf)
    #pragma unroll
    for (int nf = 0; nf < 4; ++nf)
      #pragma unroll
      for (int rr = 0; rr < 4; ++rr) {
        int r = wm * 32 + mf * 16 + g2 * 4 + rr;
        int c = wn * 64 + nf * 16 + lr;
        pp[r * 128 + c] = acc[mf][nf][rr];
      }
}

// ---- fused tail: reduce 8 split-K partials + bias + relu -> fc2 -> out ----
__global__ __launch_bounds__(256) void k_tail(const float* __restrict__ part,
    const float* __restrict__ fb1, const float* __restrict__ fw2,
    const float* __restrict__ fb2, float* __restrict__ out,
    int nr, int nrpad) {
  __shared__ float sh[2][128];
  int t = threadIdx.x;
  int r = t >> 7, c = t & 127;
  int row = blockIdx.x * 2 + r;
  size_t stride = (size_t)nrpad * 128;
  if (row < nr) {
    size_t i = (size_t)row * 128 + c;
    float s = 0.f;
    #pragma unroll
    for (int j = 0; j < SPLITK; ++j) s += part[j * stride + i];
    sh[r][c] = fmaxf(s + fb1[c], 0.f);
  }
  __syncthreads();
  if (t < 20) {
    int rr = t / 10, j = t - rr * 10;
    int orow = blockIdx.x * 2 + rr;
    if (orow < nr) {
      const float4* hv = (const float4*)sh[rr];
      const float4* wv = (const float4*)(fw2 + (size_t)j * 128);
      float s = 0.f;
      #pragma unroll
      for (int q = 0; q < 32; ++q) {
        float4 h4 = hv[q];
        float4 w4 = wv[q];
        s = fmaf(h4.x, w4.x, s);
        s = fmaf(h4.y, w4.y, s);
        s = fmaf(h4.z, w4.z, s);
        s = fmaf(h4.w, w4.w, s);
      }
      out[(size_t)orow * 10 + j] = s + fb2[j];
    }
  }
}

extern "C" void kernel_launch(void* const* d_in, const int* in_sizes, int n_in,
                              void* d_out, int out_size, void* d_ws, size_t ws_size,
                              hipStream_t stream) {
  const float* x   = (const float*)d_in[0];
  const float* w1  = (const float*)d_in[1];
  const float* b1  = (const float*)d_in[2];
  const float* w2  = (const float*)d_in[3];
  const float* b2  = (const float*)d_in[4];
  const float* fw1 = (const float*)d_in[5];
  const float* fb1 = (const float*)d_in[6];
  const float* fw2 = (const float*)d_in[7];
  const float* fb2 = (const float*)d_in[8];
  float* out = (float*)d_out;

  const int B = in_sizes[0] / 784;

  unsigned short* wt2 = (unsigned short*)d_ws;                        // 36864 B
  unsigned short* fw1t = (unsigned short*)((char*)d_ws + WT2_BYTES);  // 2359296 B
  const size_t carve = WT2_BYTES + (size_t)9216 * 128 * 2;
  char* base = (char*)d_ws + carve;
  size_t avail = (ws_size > carve) ? ws_size - carve : 0;
  const size_t per_img = (size_t)POOLN * 2 + SPLITK * 512;  // pooled + partials
  int Bc = (int)(avail / per_img);
  if (Bc > B) Bc = B;
  Bc &= ~63;
  if (Bc < 64) Bc = 64;

  unsigned short* pooled = (unsigned short*)base;
  float* part = (float*)(base + (size_t)Bc * (POOLN * 2));

  k_wt2<<<(WT2_ELEMS + 255) / 256, 256, 0, stream>>>(w2, wt2);
  k_fw1t<<<128, 256, 0, stream>>>(fw1, fw1t);

  for (int i0 = 0; i0 < B; i0 += Bc) {
    int nr = (B - i0 < Bc) ? (B - i0) : Bc;
    int mtiles = (nr + 63) / 64;
    int nrpad = mtiles * 64;
    kc_fused<<<dim3(nr, 3), 256, 0, stream>>>(x + (size_t)i0 * 784, w1, b1,
                                              wt2, b2, pooled);
    k3_fc1_mfma<<<dim3(mtiles, SPLITK), 256, 0, stream>>>(pooled, fw1t, part, nrpad);
    k_tail<<<(nr + 1) / 2, 256, 0, stream>>>(part, fb1, fw2, fb2,
                                             out + (size_t)i0 * 10, nr, nrpad);
  }
}

// Round 18
// 147.159 us; speedup vs baseline: 1.1663x; 1.0074x over previous
//
#include <hip/hip_runtime.h>
#include <hip/hip_bf16.h>
#include <string.h>

using short8 = __attribute__((ext_vector_type(8))) short;
using f32x4  = __attribute__((ext_vector_type(4))) float;
using f32x2  = __attribute__((ext_vector_type(2))) float;

#define POOLN     9216       // 144*64 elements (bf16) per image
#define FC1N      128
#define WT2_ELEMS 18432      // 36*64*8
#define WT2_BYTES 36864
#define H1S_STRIDE 36        // shorts per position row (72 B)
#define XS_STRIDE  29        // floats per x row (odd -> conflict-free)
#define SPLITK    8

#define GLL16(gp, lp) __builtin_amdgcn_global_load_lds( \
    (const __attribute__((address_space(1))) void*)(gp), \
    (__attribute__((address_space(3))) void*)(lp), 16, 0, 0)

static __device__ __forceinline__ unsigned short f2bf(float f) {
  unsigned int u = __builtin_bit_cast(unsigned int, f);
  unsigned int r = (u + 0x7FFFu + ((u >> 16) & 1u)) >> 16;
  return (unsigned short)r;
}

// packed RNE pair convert -> v_cvt_pk_bf16_f32
static __device__ __forceinline__ unsigned int pkbf(float lo, float hi) {
  __hip_bfloat162 h2 = __float22bfloat162_rn(make_float2(lo, hi));
  unsigned int r;
  memcpy(&r, &h2, sizeof(r));
  return r;
}

// ---- one-off: w2 fp32 [64][32][9] -> wt2 bf16 fragment order [(tap*4+n)][lane][8]
__global__ __launch_bounds__(256) void k_wt2(const float* __restrict__ w2,
    unsigned short* __restrict__ wt2) {
  int idx = blockIdx.x * 256 + threadIdx.x;
  if (idx >= WT2_ELEMS) return;
  int j = idx & 7;
  int l = (idx >> 3) & 63;
  int tn = idx >> 9;            // 0..35
  int tap = tn >> 2, n = tn & 3;
  int oc = n * 16 + (l & 15);
  int ic = (l >> 4) * 8 + j;
  wt2[idx] = f2bf(w2[oc * 288 + ic * 9 + tap]);
}

// ---- one-off: fc1_w [128][9216 (oc*144+sp)] -> fw1t bf16 [128][9216 (sp*64+oc)]
// Direct, no LDS: 2 elems/thread (same sp, oc pair), coalesced u32 writes.
// Reads stride 576B; L2 absorbs (4.7 MB unique). grid = 2304 blocks.
__global__ __launch_bounds__(256) void k_fw1t(const float* __restrict__ w,
    unsigned int* __restrict__ wt) {
  int idx = blockIdx.x * 256 + threadIdx.x;      // over 128*9216/2 pairs
  int c = idx / 4608;                            // output row (fc1 unit)
  int k2 = idx - c * 4608;                       // pair index within row
  int k = k2 * 2;                                // k = sp*64 + oc, oc even
  int oc = k & 63;
  int sp = k >> 6;
  const float* src = w + (size_t)c * 9216;
  float lo = src[oc * 144 + sp];
  float hi = src[(oc + 1) * 144 + sp];
  wt[idx] = pkbf(lo, hi);
}

// ---- fused conv1+relu+conv2+relu+maxpool, row-thirds (best config) ----
// grid (nr, 3). conv1 packed fp32 channel pairs; conv2 wave = local pooled
// row, acc[3][4]=48 AGPR. LDS 20.1 KB, (256,4). T5 setprio around MFMA.
__global__ __launch_bounds__(256, 4) void kc_fused(const float* __restrict__ x,
    const float* __restrict__ w1, const float* __restrict__ b1,
    const unsigned short* __restrict__ wt2, const float* __restrict__ b2,
    unsigned short* __restrict__ pooled) {
  int img = blockIdx.x;
  int tt = blockIdx.y;
  __shared__ float xs[12 * XS_STRIDE];                            // 1392 B
  __shared__ __align__(16) unsigned short h1s[260 * H1S_STRIDE];  // 18720 B
  int t = threadIdx.x;
  int wv = t >> 6, ln = t & 63;
  int r0x = tt * 8;                      // first x/h1 global row of this third

  const float* xp = x + (size_t)img * 784 + (size_t)r0x * 28;
  for (int i = t; i < 12 * 28; i += 256) {
    int r = i / 28, c = i - r * 28;
    xs[r * XS_STRIDE + c] = xp[r * 28 + c];
  }

  // conv1 weights as channel-pair f32x2 (wave-uniform -> SGPR pairs)
  int wvu = __builtin_amdgcn_readfirstlane(wv);
  f32x2 wp[4][9], bp[4];
  #pragma unroll
  for (int p = 0; p < 4; ++p) {
    int o = wvu * 8 + p * 2;
    bp[p] = (f32x2){b1[o], b1[o + 1]};
    #pragma unroll
    for (int q = 0; q < 9; ++q)
      wp[p][q] = (f32x2){w1[o * 9 + q], w1[(o + 1) * 9 + q]};
  }
  __syncthreads();

  // conv1: lane -> column, 2 halves x 5 rows each (local h1 rows 0..9)
  if (ln < 52) {
    int half = (ln >= 26);
    int xcol = ln - half * 26;          // 0..25
    int y0 = half * 5;                  // local row base
    float win[3][3];
    #pragma unroll
    for (int c = 0; c < 3; ++c) {
      win[1][c] = xs[(y0 + 0) * XS_STRIDE + xcol + c];
      win[2][c] = xs[(y0 + 1) * XS_STRIDE + xcol + c];
    }
    #pragma unroll
    for (int i = 0; i < 5; ++i) {
      #pragma unroll
      for (int c = 0; c < 3; ++c) {
        win[0][c] = win[1][c];
        win[1][c] = win[2][c];
        win[2][c] = xs[(y0 + i + 2) * XS_STRIDE + xcol + c];
      }
      f32x2 s[4] = {bp[0], bp[1], bp[2], bp[3]};
      #pragma unroll
      for (int r = 0; r < 3; ++r)
        #pragma unroll
        for (int c = 0; c < 3; ++c) {
          f32x2 wv2 = (f32x2){win[r][c], win[r][c]};
          #pragma unroll
          for (int p = 0; p < 4; ++p)
            s[p] = __builtin_elementwise_fma(wv2, wp[p][r * 3 + c], s[p]);
        }
      unsigned int packed[4];
      const f32x2 z2 = (f32x2){0.f, 0.f};
      #pragma unroll
      for (int p = 0; p < 4; ++p) {
        f32x2 sp = __builtin_elementwise_max(s[p], z2);
        packed[p] = pkbf(sp.x, sp.y);
      }
      int pos = (y0 + i) * 26 + xcol;
      unsigned short* dst = &h1s[pos * H1S_STRIDE + wv * 8];
      *(uint2*)dst = make_uint2(packed[0], packed[1]);
      *(uint2*)(dst + 4) = make_uint2(packed[2], packed[3]);
    }
  }
  __syncthreads();

  // ---- conv2 + pool: wave = local pooled row, 3 m-tiles ----
  int col = ln & 15;
  int g = (ln >> 4) & 3;

  int abase[3];
  #pragma unroll
  for (int i = 0; i < 3; ++i) {
    int y = 2 * wv + (col & 1);                    // local h1 row
    int xx = 8 * i + (col >> 1);
    abase[i] = (y * 26 + xx) * (H1S_STRIDE * 2) + g * 16;
  }

  f32x4 acc[3][4];
  #pragma unroll
  for (int m = 0; m < 3; ++m)
    #pragma unroll
    for (int n = 0; n < 4; ++n)
      acc[m][n] = (f32x4){0.f, 0.f, 0.f, 0.f};

  const char* hsb = (const char*)h1s;
  __builtin_amdgcn_s_setprio(1);
  #pragma unroll
  for (int tap = 0; tap < 9; ++tap) {
    int ky = tap / 3, kx = tap - ky * 3;
    int toff = (ky * 26 + kx) * (H1S_STRIDE * 2);
    short8 bf[4];
    #pragma unroll
    for (int n = 0; n < 4; ++n)
      bf[n] = *(const short8*)(wt2 + ((size_t)(tap * 4 + n) * 64 + ln) * 8);
    #pragma unroll
    for (int m = 0; m < 3; ++m) {
      union { short8 v; uint2 d[2]; } af;
      af.d[0] = *(const uint2*)(hsb + abase[m] + toff);
      af.d[1] = *(const uint2*)(hsb + abase[m] + toff + 8);
      #pragma unroll
      for (int n = 0; n < 4; ++n)
        acc[m][n] = __builtin_amdgcn_mfma_f32_16x16x32_bf16(af.v, bf[n], acc[m][n], 0, 0, 0);
    }
  }
  __builtin_amdgcn_s_setprio(0);

  float bias[4];
  #pragma unroll
  for (int n = 0; n < 4; ++n) bias[n] = b2[n * 16 + col];
  unsigned short* pp = pooled + (size_t)img * POOLN;
  int pr = tt * 4 + wv;                            // global pooled row
  #pragma unroll
  for (int m = 0; m < 3; ++m) {
    int sp = pr * 12 + m * 4 + g;
    float rv[4];
    #pragma unroll
    for (int n = 0; n < 4; ++n) {
      f32x4 a = acc[m][n];
      float v = fmaxf(fmaxf(a[0], a[1]), fmaxf(a[2], a[3]));
      rv[n] = fmaxf(v + bias[n], 0.f);
    }
    unsigned int p01 = pkbf(rv[0], rv[1]);
    unsigned int p23 = pkbf(rv[2], rv[3]);
    unsigned short* pr0 = pp + sp * 64 + col;
    pr0[0]  = (unsigned short)p01;
    pr0[16] = (unsigned short)(p01 >> 16);
    pr0[32] = (unsigned short)p23;
    pr0[48] = (unsigned short)(p23 >> 16);
  }
}

// ---- fc1 via MFMA, split-K=8: pooled bf16 [nr][9216] @ fw1t bf16 [128][9216]^T
// grid (nrpad/64, 8); each group does 1152 K-elems = 18 steps of 64.
__global__ __launch_bounds__(256) void k3_fc1_mfma(
    const unsigned short* __restrict__ a, const unsigned short* __restrict__ w,
    float* __restrict__ part, int nrpad) {
  __shared__ __align__(16) unsigned short As[2][4096];   // [64][64] bf16 x2
  __shared__ __align__(16) unsigned short Bs[2][8192];   // [128][64] bf16 x2
  int row0 = blockIdx.x * 64;
  int kbase = blockIdx.y * 1152;
  int t = threadIdx.x;
  int wv = t >> 6, l = t & 63;
  int rsub = l >> 3;
  int src_sw = ((l & 7) ^ rsub) << 4;

  const char* abase = (const char*)a + (size_t)row0 * 18432;
  const char* bbase = (const char*)w;

  auto stage = [&](int buf, int step) {
    size_t k0b = (size_t)(kbase + step * 64) * 2;
    #pragma unroll
    for (int i = 0; i < 2; ++i) {
      int c = wv * 2 + i;
      GLL16(abase + (size_t)(c * 8 + rsub) * 18432 + k0b + src_sw,
            (char*)As[buf] + c * 1024);
    }
    #pragma unroll
    for (int i = 0; i < 4; ++i) {
      int c = wv * 4 + i;
      GLL16(bbase + (size_t)(c * 8 + rsub) * 18432 + k0b + src_sw,
            (char*)Bs[buf] + c * 1024);
    }
  };

  int wm = wv >> 1, wn = wv & 1;
  int lr = l & 15, g2 = l >> 4;
  int rdxor = (lr & 7) << 4;

  f32x4 acc[2][4];
  #pragma unroll
  for (int mf = 0; mf < 2; ++mf)
    #pragma unroll
    for (int nf = 0; nf < 4; ++nf)
      acc[mf][nf] = (f32x4){0.f, 0.f, 0.f, 0.f};

  stage(0, 0);
  __syncthreads();
  for (int s = 0; s < 18; ++s) {
    int cur = s & 1;
    if (s < 17) stage(cur ^ 1, s + 1);
    const char* Ab = (const char*)As[cur];
    const char* Bb = (const char*)Bs[cur];
    #pragma unroll
    for (int ksub = 0; ksub < 2; ++ksub) {
      int koff = (ksub * 64 + g2 * 16) ^ rdxor;
      short8 af0 = *(const short8*)(Ab + (wm * 32 + lr) * 128 + koff);
      short8 af1 = *(const short8*)(Ab + (wm * 32 + 16 + lr) * 128 + koff);
      short8 bf[4];
      #pragma unroll
      for (int nf = 0; nf < 4; ++nf)
        bf[nf] = *(const short8*)(Bb + (wn * 64 + nf * 16 + lr) * 128 + koff);
      #pragma unroll
      for (int nf = 0; nf < 4; ++nf) {
        acc[0][nf] = __builtin_amdgcn_mfma_f32_16x16x32_bf16(af0, bf[nf], acc[0][nf], 0, 0, 0);
        acc[1][nf] = __builtin_amdgcn_mfma_f32_16x16x32_bf16(af1, bf[nf], acc[1][nf], 0, 0, 0);
      }
    }
    __syncthreads();
  }

  float* pp = part + (size_t)blockIdx.y * nrpad * 128 + (size_t)row0 * 128;
  #pragma unroll
  for (int mf = 0; mf < 2; ++mf)
    #pragma unroll
    for (int nf = 0; nf < 4; ++nf)
      #pragma unroll
      for (int rr = 0; rr < 4; ++rr) {
        int r = wm * 32 + mf * 16 + g2 * 4 + rr;
        int c = wn * 64 + nf * 16 + lr;
        pp[r * 128 + c] = acc[mf][nf][rr];
      }
}

// ---- fused tail: reduce 8 split-K partials + bias + relu -> fc2 -> out ----
__global__ __launch_bounds__(256) void k_tail(const float* __restrict__ part,
    const float* __restrict__ fb1, const float* __restrict__ fw2,
    const float* __restrict__ fb2, float* __restrict__ out,
    int nr, int nrpad) {
  __shared__ float sh[2][128];
  int t = threadIdx.x;
  int r = t >> 7, c = t & 127;
  int row = blockIdx.x * 2 + r;
  size_t stride = (size_t)nrpad * 128;
  if (row < nr) {
    size_t i = (size_t)row * 128 + c;
    float s = 0.f;
    #pragma unroll
    for (int j = 0; j < SPLITK; ++j) s += part[j * stride + i];
    sh[r][c] = fmaxf(s + fb1[c], 0.f);
  }
  __syncthreads();
  if (t < 20) {
    int rr = t / 10, j = t - rr * 10;
    int orow = blockIdx.x * 2 + rr;
    if (orow < nr) {
      const float4* hv = (const float4*)sh[rr];
      const float4* wv = (const float4*)(fw2 + (size_t)j * 128);
      float s = 0.f;
      #pragma unroll
      for (int q = 0; q < 32; ++q) {
        float4 h4 = hv[q];
        float4 w4 = wv[q];
        s = fmaf(h4.x, w4.x, s);
        s = fmaf(h4.y, w4.y, s);
        s = fmaf(h4.z, w4.z, s);
        s = fmaf(h4.w, w4.w, s);
      }
      out[(size_t)orow * 10 + j] = s + fb2[j];
    }
  }
}

extern "C" void kernel_launch(void* const* d_in, const int* in_sizes, int n_in,
                              void* d_out, int out_size, void* d_ws, size_t ws_size,
                              hipStream_t stream) {
  const float* x   = (const float*)d_in[0];
  const float* w1  = (const float*)d_in[1];
  const float* b1  = (const float*)d_in[2];
  const float* w2  = (const float*)d_in[3];
  const float* b2  = (const float*)d_in[4];
  const float* fw1 = (const float*)d_in[5];
  const float* fb1 = (const float*)d_in[6];
  const float* fw2 = (const float*)d_in[7];
  const float* fb2 = (const float*)d_in[8];
  float* out = (float*)d_out;

  const int B = in_sizes[0] / 784;

  unsigned short* wt2 = (unsigned short*)d_ws;                        // 36864 B
  unsigned short* fw1t = (unsigned short*)((char*)d_ws + WT2_BYTES);  // 2359296 B
  const size_t carve = WT2_BYTES + (size_t)9216 * 128 * 2;
  char* base = (char*)d_ws + carve;
  size_t avail = (ws_size > carve) ? ws_size - carve : 0;
  const size_t per_img = (size_t)POOLN * 2 + SPLITK * 512;  // pooled + partials
  int Bc = (int)(avail / per_img);
  if (Bc > B) Bc = B;
  Bc &= ~63;
  if (Bc < 64) Bc = 64;

  unsigned short* pooled = (unsigned short*)base;
  float* part = (float*)(base + (size_t)Bc * (POOLN * 2));

  k_wt2<<<(WT2_ELEMS + 255) / 256, 256, 0, stream>>>(w2, wt2);
  k_fw1t<<<2304, 256, 0, stream>>>(fw1, (unsigned int*)fw1t);

  for (int i0 = 0; i0 < B; i0 += Bc) {
    int nr = (B - i0 < Bc) ? (B - i0) : Bc;
    int mtiles = (nr + 63) / 64;
    int nrpad = mtiles * 64;
    kc_fused<<<dim3(nr, 3), 256, 0, stream>>>(x + (size_t)i0 * 784, w1, b1,
                                              wt2, b2, pooled);
    k3_fc1_mfma<<<dim3(mtiles, SPLITK), 256, 0, stream>>>(pooled, fw1t, part, nrpad);
    k_tail<<<(nr + 1) / 2, 256, 0, stream>>>(part, fb1, fw2, fb2,
                                             out + (size_t)i0 * 10, nr, nrpad);
  }
}

// Round 19
// 146.355 us; speedup vs baseline: 1.1727x; 1.0055x over previous
//
#include <hip/hip_runtime.h>
#include <hip/hip_bf16.h>
#include <string.h>

using short8 = __attribute__((ext_vector_type(8))) short;
using f32x4  = __attribute__((ext_vector_type(4))) float;
using f32x2  = __attribute__((ext_vector_type(2))) float;

#define POOLN     9216       // 144*64 elements (bf16) per image
#define FC1N      128
#define WT2_ELEMS 18432      // 36*64*8
#define WT2_BYTES 36864
#define FW1_PAIRS 589824     // 128*9216/2
#define H1S_STRIDE 36        // shorts per position row (72 B)
#define XS_STRIDE  29        // floats per x row (odd -> conflict-free)
#define SPLITK    16

#define GLL16(gp, lp) __builtin_amdgcn_global_load_lds( \
    (const __attribute__((address_space(1))) void*)(gp), \
    (__attribute__((address_space(3))) void*)(lp), 16, 0, 0)

static __device__ __forceinline__ unsigned short f2bf(float f) {
  unsigned int u = __builtin_bit_cast(unsigned int, f);
  unsigned int r = (u + 0x7FFFu + ((u >> 16) & 1u)) >> 16;
  return (unsigned short)r;
}

// packed RNE pair convert -> v_cvt_pk_bf16_f32
static __device__ __forceinline__ unsigned int pkbf(float lo, float hi) {
  __hip_bfloat162 h2 = __float22bfloat162_rn(make_float2(lo, hi));
  unsigned int r;
  memcpy(&r, &h2, sizeof(r));
  return r;
}

// ---- one-off preprocessing (merged): w2 -> wt2 frag order; fc1_w -> fw1t ----
// wt2: [(tap*4+n)][lane][8] bf16.  fw1t: [128][9216 (sp*64+oc)] bf16, pair-packed.
__global__ __launch_bounds__(256) void k_prep(const float* __restrict__ w2,
    unsigned short* __restrict__ wt2, const float* __restrict__ fw1,
    unsigned int* __restrict__ fw1t) {
  int idx = blockIdx.x * 256 + threadIdx.x;
  if (idx < WT2_ELEMS) {
    int j = idx & 7;
    int l = (idx >> 3) & 63;
    int tn = idx >> 9;            // 0..35
    int tap = tn >> 2, n = tn & 3;
    int oc = n * 16 + (l & 15);
    int ic = (l >> 4) * 8 + j;
    wt2[idx] = f2bf(w2[oc * 288 + ic * 9 + tap]);
  }
  int fidx = idx - WT2_ELEMS;
  if (fidx >= 0 && fidx < FW1_PAIRS) {
    int c = fidx / 4608;                           // fc1 unit (output row)
    int k2 = fidx - c * 4608;                      // pair index within row
    int k = k2 * 2;                                // k = sp*64 + oc, oc even
    int oc = k & 63;
    int sp = k >> 6;
    const float* src = fw1 + (size_t)c * 9216;
    float lo = src[oc * 144 + sp];
    float hi = src[(oc + 1) * 144 + sp];
    fw1t[fidx] = pkbf(lo, hi);
  }
}

// ---- fused conv1+relu+conv2+relu+maxpool, row-thirds (best config) ----
// grid (nr, 3). conv1 packed fp32 channel pairs; conv2 wave = local pooled
// row, acc[3][4]=48 AGPR. LDS 20.1 KB, (256,4). T5 setprio around MFMA.
__global__ __launch_bounds__(256, 4) void kc_fused(const float* __restrict__ x,
    const float* __restrict__ w1, const float* __restrict__ b1,
    const unsigned short* __restrict__ wt2, const float* __restrict__ b2,
    unsigned short* __restrict__ pooled) {
  int img = blockIdx.x;
  int tt = blockIdx.y;
  __shared__ float xs[12 * XS_STRIDE];                            // 1392 B
  __shared__ __align__(16) unsigned short h1s[260 * H1S_STRIDE];  // 18720 B
  int t = threadIdx.x;
  int wv = t >> 6, ln = t & 63;
  int r0x = tt * 8;                      // first x/h1 global row of this third

  const float* xp = x + (size_t)img * 784 + (size_t)r0x * 28;
  for (int i = t; i < 12 * 28; i += 256) {
    int r = i / 28, c = i - r * 28;
    xs[r * XS_STRIDE + c] = xp[r * 28 + c];
  }

  // conv1 weights as channel-pair f32x2 (wave-uniform -> SGPR pairs)
  int wvu = __builtin_amdgcn_readfirstlane(wv);
  f32x2 wp[4][9], bp[4];
  #pragma unroll
  for (int p = 0; p < 4; ++p) {
    int o = wvu * 8 + p * 2;
    bp[p] = (f32x2){b1[o], b1[o + 1]};
    #pragma unroll
    for (int q = 0; q < 9; ++q)
      wp[p][q] = (f32x2){w1[o * 9 + q], w1[(o + 1) * 9 + q]};
  }
  __syncthreads();

  // conv1: lane -> column, 2 halves x 5 rows each (local h1 rows 0..9)
  if (ln < 52) {
    int half = (ln >= 26);
    int xcol = ln - half * 26;          // 0..25
    int y0 = half * 5;                  // local row base
    float win[3][3];
    #pragma unroll
    for (int c = 0; c < 3; ++c) {
      win[1][c] = xs[(y0 + 0) * XS_STRIDE + xcol + c];
      win[2][c] = xs[(y0 + 1) * XS_STRIDE + xcol + c];
    }
    #pragma unroll
    for (int i = 0; i < 5; ++i) {
      #pragma unroll
      for (int c = 0; c < 3; ++c) {
        win[0][c] = win[1][c];
        win[1][c] = win[2][c];
        win[2][c] = xs[(y0 + i + 2) * XS_STRIDE + xcol + c];
      }
      f32x2 s[4] = {bp[0], bp[1], bp[2], bp[3]};
      #pragma unroll
      for (int r = 0; r < 3; ++r)
        #pragma unroll
        for (int c = 0; c < 3; ++c) {
          f32x2 wv2 = (f32x2){win[r][c], win[r][c]};
          #pragma unroll
          for (int p = 0; p < 4; ++p)
            s[p] = __builtin_elementwise_fma(wv2, wp[p][r * 3 + c], s[p]);
        }
      unsigned int packed[4];
      const f32x2 z2 = (f32x2){0.f, 0.f};
      #pragma unroll
      for (int p = 0; p < 4; ++p) {
        f32x2 sp = __builtin_elementwise_max(s[p], z2);
        packed[p] = pkbf(sp.x, sp.y);
      }
      int pos = (y0 + i) * 26 + xcol;
      unsigned short* dst = &h1s[pos * H1S_STRIDE + wv * 8];
      *(uint2*)dst = make_uint2(packed[0], packed[1]);
      *(uint2*)(dst + 4) = make_uint2(packed[2], packed[3]);
    }
  }
  __syncthreads();

  // ---- conv2 + pool: wave = local pooled row, 3 m-tiles ----
  int col = ln & 15;
  int g = (ln >> 4) & 3;

  int abase[3];
  #pragma unroll
  for (int i = 0; i < 3; ++i) {
    int y = 2 * wv + (col & 1);                    // local h1 row
    int xx = 8 * i + (col >> 1);
    abase[i] = (y * 26 + xx) * (H1S_STRIDE * 2) + g * 16;
  }

  f32x4 acc[3][4];
  #pragma unroll
  for (int m = 0; m < 3; ++m)
    #pragma unroll
    for (int n = 0; n < 4; ++n)
      acc[m][n] = (f32x4){0.f, 0.f, 0.f, 0.f};

  const char* hsb = (const char*)h1s;
  __builtin_amdgcn_s_setprio(1);
  #pragma unroll
  for (int tap = 0; tap < 9; ++tap) {
    int ky = tap / 3, kx = tap - ky * 3;
    int toff = (ky * 26 + kx) * (H1S_STRIDE * 2);
    short8 bf[4];
    #pragma unroll
    for (int n = 0; n < 4; ++n)
      bf[n] = *(const short8*)(wt2 + ((size_t)(tap * 4 + n) * 64 + ln) * 8);
    #pragma unroll
    for (int m = 0; m < 3; ++m) {
      union { short8 v; uint2 d[2]; } af;
      af.d[0] = *(const uint2*)(hsb + abase[m] + toff);
      af.d[1] = *(const uint2*)(hsb + abase[m] + toff + 8);
      #pragma unroll
      for (int n = 0; n < 4; ++n)
        acc[m][n] = __builtin_amdgcn_mfma_f32_16x16x32_bf16(af.v, bf[n], acc[m][n], 0, 0, 0);
    }
  }
  __builtin_amdgcn_s_setprio(0);

  float bias[4];
  #pragma unroll
  for (int n = 0; n < 4; ++n) bias[n] = b2[n * 16 + col];
  unsigned short* pp = pooled + (size_t)img * POOLN;
  int pr = tt * 4 + wv;                            // global pooled row
  #pragma unroll
  for (int m = 0; m < 3; ++m) {
    int sp = pr * 12 + m * 4 + g;
    float rv[4];
    #pragma unroll
    for (int n = 0; n < 4; ++n) {
      f32x4 a = acc[m][n];
      float v = fmaxf(fmaxf(a[0], a[1]), fmaxf(a[2], a[3]));
      rv[n] = fmaxf(v + bias[n], 0.f);
    }
    unsigned int p01 = pkbf(rv[0], rv[1]);
    unsigned int p23 = pkbf(rv[2], rv[3]);
    unsigned short* pr0 = pp + sp * 64 + col;
    pr0[0]  = (unsigned short)p01;
    pr0[16] = (unsigned short)(p01 >> 16);
    pr0[32] = (unsigned short)p23;
    pr0[48] = (unsigned short)(p23 >> 16);
  }
}

// ---- fc1 via MFMA, split-K=16: pooled bf16 [nr][9216] @ fw1t bf16 [128][9216]^T
// grid (nrpad/64, 16); each group does 576 K-elems = 9 steps of 64.
__global__ __launch_bounds__(256) void k3_fc1_mfma(
    const unsigned short* __restrict__ a, const unsigned short* __restrict__ w,
    float* __restrict__ part, int nrpad) {
  __shared__ __align__(16) unsigned short As[2][4096];   // [64][64] bf16 x2
  __shared__ __align__(16) unsigned short Bs[2][8192];   // [128][64] bf16 x2
  int row0 = blockIdx.x * 64;
  int kbase = blockIdx.y * 576;
  int t = threadIdx.x;
  int wv = t >> 6, l = t & 63;
  int rsub = l >> 3;
  int src_sw = ((l & 7) ^ rsub) << 4;

  const char* abase = (const char*)a + (size_t)row0 * 18432;
  const char* bbase = (const char*)w;

  auto stage = [&](int buf, int step) {
    size_t k0b = (size_t)(kbase + step * 64) * 2;
    #pragma unroll
    for (int i = 0; i < 2; ++i) {
      int c = wv * 2 + i;
      GLL16(abase + (size_t)(c * 8 + rsub) * 18432 + k0b + src_sw,
            (char*)As[buf] + c * 1024);
    }
    #pragma unroll
    for (int i = 0; i < 4; ++i) {
      int c = wv * 4 + i;
      GLL16(bbase + (size_t)(c * 8 + rsub) * 18432 + k0b + src_sw,
            (char*)Bs[buf] + c * 1024);
    }
  };

  int wm = wv >> 1, wn = wv & 1;
  int lr = l & 15, g2 = l >> 4;
  int rdxor = (lr & 7) << 4;

  f32x4 acc[2][4];
  #pragma unroll
  for (int mf = 0; mf < 2; ++mf)
    #pragma unroll
    for (int nf = 0; nf < 4; ++nf)
      acc[mf][nf] = (f32x4){0.f, 0.f, 0.f, 0.f};

  stage(0, 0);
  __syncthreads();
  for (int s = 0; s < 9; ++s) {
    int cur = s & 1;
    if (s < 8) stage(cur ^ 1, s + 1);
    const char* Ab = (const char*)As[cur];
    const char* Bb = (const char*)Bs[cur];
    #pragma unroll
    for (int ksub = 0; ksub < 2; ++ksub) {
      int koff = (ksub * 64 + g2 * 16) ^ rdxor;
      short8 af0 = *(const short8*)(Ab + (wm * 32 + lr) * 128 + koff);
      short8 af1 = *(const short8*)(Ab + (wm * 32 + 16 + lr) * 128 + koff);
      short8 bf[4];
      #pragma unroll
      for (int nf = 0; nf < 4; ++nf)
        bf[nf] = *(const short8*)(Bb + (wn * 64 + nf * 16 + lr) * 128 + koff);
      #pragma unroll
      for (int nf = 0; nf < 4; ++nf) {
        acc[0][nf] = __builtin_amdgcn_mfma_f32_16x16x32_bf16(af0, bf[nf], acc[0][nf], 0, 0, 0);
        acc[1][nf] = __builtin_amdgcn_mfma_f32_16x16x32_bf16(af1, bf[nf], acc[1][nf], 0, 0, 0);
      }
    }
    __syncthreads();
  }

  float* pp = part + (size_t)blockIdx.y * nrpad * 128 + (size_t)row0 * 128;
  #pragma unroll
  for (int mf = 0; mf < 2; ++mf)
    #pragma unroll
    for (int nf = 0; nf < 4; ++nf)
      #pragma unroll
      for (int rr = 0; rr < 4; ++rr) {
        int r = wm * 32 + mf * 16 + g2 * 4 + rr;
        int c = wn * 64 + nf * 16 + lr;
        pp[r * 128 + c] = acc[mf][nf][rr];
      }
}

// ---- fused tail: reduce 16 split-K partials + bias + relu -> fc2 -> out ----
__global__ __launch_bounds__(256) void k_tail(const float* __restrict__ part,
    const float* __restrict__ fb1, const float* __restrict__ fw2,
    const float* __restrict__ fb2, float* __restrict__ out,
    int nr, int nrpad) {
  __shared__ float sh[2][128];
  int t = threadIdx.x;
  int r = t >> 7, c = t & 127;
  int row = blockIdx.x * 2 + r;
  size_t stride = (size_t)nrpad * 128;
  if (row < nr) {
    size_t i = (size_t)row * 128 + c;
    float s = 0.f;
    #pragma unroll
    for (int j = 0; j < SPLITK; ++j) s += part[j * stride + i];
    sh[r][c] = fmaxf(s + fb1[c], 0.f);
  }
  __syncthreads();
  if (t < 20) {
    int rr = t / 10, j = t - rr * 10;
    int orow = blockIdx.x * 2 + rr;
    if (orow < nr) {
      const float4* hv = (const float4*)sh[rr];
      const float4* wv = (const float4*)(fw2 + (size_t)j * 128);
      float s = 0.f;
      #pragma unroll
      for (int q = 0; q < 32; ++q) {
        float4 h4 = hv[q];
        float4 w4 = wv[q];
        s = fmaf(h4.x, w4.x, s);
        s = fmaf(h4.y, w4.y, s);
        s = fmaf(h4.z, w4.z, s);
        s = fmaf(h4.w, w4.w, s);
      }
      out[(size_t)orow * 10 + j] = s + fb2[j];
    }
  }
}

extern "C" void kernel_launch(void* const* d_in, const int* in_sizes, int n_in,
                              void* d_out, int out_size, void* d_ws, size_t ws_size,
                              hipStream_t stream) {
  const float* x   = (const float*)d_in[0];
  const float* w1  = (const float*)d_in[1];
  const float* b1  = (const float*)d_in[2];
  const float* w2  = (const float*)d_in[3];
  const float* b2  = (const float*)d_in[4];
  const float* fw1 = (const float*)d_in[5];
  const float* fb1 = (const float*)d_in[6];
  const float* fw2 = (const float*)d_in[7];
  const float* fb2 = (const float*)d_in[8];
  float* out = (float*)d_out;

  const int B = in_sizes[0] / 784;

  unsigned short* wt2 = (unsigned short*)d_ws;                        // 36864 B
  unsigned short* fw1t = (unsigned short*)((char*)d_ws + WT2_BYTES);  // 2359296 B
  const size_t carve = WT2_BYTES + (size_t)9216 * 128 * 2;
  char* base = (char*)d_ws + carve;
  size_t avail = (ws_size > carve) ? ws_size - carve : 0;
  const size_t per_img = (size_t)POOLN * 2 + SPLITK * 512;  // pooled + partials
  int Bc = (int)(avail / per_img);
  if (Bc > B) Bc = B;
  Bc &= ~63;
  if (Bc < 64) Bc = 64;

  unsigned short* pooled = (unsigned short*)base;
  float* part = (float*)(base + (size_t)Bc * (POOLN * 2));

  k_prep<<<(WT2_ELEMS + FW1_PAIRS + 255) / 256, 256, 0, stream>>>(
      w2, wt2, fw1, (unsigned int*)fw1t);

  for (int i0 = 0; i0 < B; i0 += Bc) {
    int nr = (B - i0 < Bc) ? (B - i0) : Bc;
    int mtiles = (nr + 63) / 64;
    int nrpad = mtiles * 64;
    kc_fused<<<dim3(nr, 3), 256, 0, stream>>>(x + (size_t)i0 * 784, w1, b1,
                                              wt2, b2, pooled);
    k3_fc1_mfma<<<dim3(mtiles, SPLITK), 256, 0, stream>>>(pooled, fw1t, part, nrpad);
    k_tail<<<(nr + 1) / 2, 256, 0, stream>>>(part, fb1, fw2, fb2,
                                             out + (size_t)i0 * 10, nr, nrpad);
  }
}